// Round 24
// baseline (309.273 us; speedup 1.0000x reference)
//
#include <hip/hip_runtime.h>
#include <hip/hip_bf16.h>
#include <math.h>

typedef __attribute__((ext_vector_type(4))) float f32x4;
typedef __attribute__((ext_vector_type(8))) __bf16 bf16x8;
typedef __attribute__((ext_vector_type(8))) unsigned short u16x8;

#define HID    2048
#define NHEADS 8
#define HDIM   256
#define SEQ    2048
#define BATCH  2
#define ROWS   (BATCH*SEQ)                 // 4096
#define QKVN   (NHEADS*HDIM + 2*HDIM)      // 2560
#define NBH    (BATCH*NHEADS)              // 16

typedef __attribute__((address_space(1))) const void gvoid_t;
typedef __attribute__((address_space(3))) void lvoid_t;

__device__ __forceinline__ void gload16(const void* g, void* l){
  __builtin_amdgcn_global_load_lds((gvoid_t*)g, (lvoid_t*)l, 16, 0, 0);
}

__device__ __forceinline__ float bf2f(unsigned short u){
  union { unsigned int i; float f; } x; x.i = ((unsigned int)u) << 16; return x.f;
}
__device__ __forceinline__ unsigned short f2bf(float f){
  union { float f; unsigned int i; } x; x.f = f;
  unsigned int u = x.i;
  return (unsigned short)((u + 0x7FFFu + ((u >> 16) & 1u)) >> 16);
}

// ============ k_prep: hs f32->bf16 convert (blocks 0..2047) ============
// ============         + batched weight transposes (blocks 2048..11263) ============
__global__ __launch_bounds__(256)
void k_prep(const float* __restrict__ hs, unsigned short* __restrict__ hsb,
            const float* __restrict__ Wq, const float* __restrict__ Wk,
            const float* __restrict__ Wv, const float* __restrict__ Wo,
            unsigned short* __restrict__ wqkvT, unsigned short* __restrict__ woT){
  int bid = (int)blockIdx.x;
  if (bid < 2048){
    long i = ((long)bid * 256 + threadIdx.x) * 16;
    f32x4 x0 = *(const f32x4*)(hs + i);
    f32x4 x1 = *(const f32x4*)(hs + i + 4);
    f32x4 x2 = *(const f32x4*)(hs + i + 8);
    f32x4 x3 = *(const f32x4*)(hs + i + 12);
    u16x8 w0, w1;
    #pragma unroll
    for (int j = 0; j < 4; ++j){
      w0[j]   = f2bf(x0[j]);
      w0[4+j] = f2bf(x1[j]);
      w1[j]   = f2bf(x2[j]);
      w1[4+j] = f2bf(x3[j]);
    }
    *(u16x8*)(hsb + i)     = w0;
    *(u16x8*)(hsb + i + 8) = w1;
    return;
  }
  // ---- weight transpose: f32 (2048 x srcCols) -> bf16 (srcCols x 2048) ----
  __shared__ float t[32][33];
  bid -= 2048;
  const float* src; unsigned short* dst; int srcCols, gx, local;
  if (bid < 4096)      { src = Wq; dst = wqkvT;                        srcCols = HID;  gx = 64; local = bid; }
  else if (bid < 4608) { src = Wk; dst = wqkvT + (long)HID*HID;        srcCols = HDIM; gx = 8;  local = bid - 4096; }
  else if (bid < 5120) { src = Wv; dst = wqkvT + (long)(HID+HDIM)*HID; srcCols = HDIM; gx = 8;  local = bid - 4608; }
  else                 { src = Wo; dst = woT;                          srcCols = HID;  gx = 64; local = bid - 5120; }
  int bx = (local % gx) * 32;
  int by = (local / gx) * 32;
  int tx = threadIdx.x & 31, ty = threadIdx.x >> 5;
  #pragma unroll
  for (int i = 0; i < 4; ++i){
    int rr = ty + i*8;
    t[rr][tx] = src[(long)(by + rr)*srcCols + bx + tx];
  }
  __syncthreads();
  #pragma unroll
  for (int i = 0; i < 4; ++i){
    int rr = ty + i*8;
    dst[(long)(bx + rr)*HID + by + tx] = f2bf(t[tx][rr]);
  }
}

// ============ k_mid: RoPE Q/K (blocks 0..4095) + V transpose (blocks 4096..5119) ============
__global__ __launch_bounds__(256)
void k_mid(const unsigned short* __restrict__ qkv, const int* __restrict__ pos_ids,
           unsigned short* __restrict__ Qb, unsigned short* __restrict__ Kb,
           unsigned short* __restrict__ VT){
  int bid = (int)blockIdx.x;
  int tid = threadIdx.x;
  if (bid < ROWS){
    int row = bid;
    float pos = (float)pos_ids[row];
    const unsigned short* r = qkv + (long)row * QKVN;
    #pragma unroll
    for (int it = 0; it < 4; ++it){
      int p = it*256 + tid;
      int d = p & 127, h = p >> 7;
      int col = h*HDIM + d;
      float inv = exp2f((float)d * -0.10381025296523132f);
      float ang = pos * inv;
      float sn, cs; sincosf(ang, &sn, &cs);
      float x0 = bf2f(r[col]), x1 = bf2f(r[col + 128]);
      Qb[(long)row*HID + col]       = f2bf(x0*cs - x1*sn);
      Qb[(long)row*HID + col + 128] = f2bf(x1*cs + x0*sn);
    }
    if (tid < 128){
      int d = tid;
      float inv = exp2f((float)d * -0.10381025296523132f);
      float ang = pos * inv;
      float sn, cs; sincosf(ang, &sn, &cs);
      float x0 = bf2f(r[HID + d]), x1 = bf2f(r[HID + d + 128]);
      Kb[(long)row*HDIM + d]       = f2bf(x0*cs - x1*sn);
      Kb[(long)row*HDIM + d + 128] = f2bf(x1*cs + x0*sn);
    }
    return;
  }
  __shared__ unsigned short t[32][34];
  int local = bid - ROWS;
  int b  = local >> 9;
  int rem = local & 511;
  int s0 = (rem >> 3) * 32;
  int d0 = (rem & 7) * 32;
  int tx = tid & 31, ty = tid >> 5;
  #pragma unroll
  for (int i = 0; i < 4; ++i){
    int rr = ty + i*8;
    t[rr][tx] = qkv[(long)(b*SEQ + s0 + rr)*QKVN + HID + HDIM + d0 + tx];
  }
  __syncthreads();
  #pragma unroll
  for (int i = 0; i < 4; ++i){
    int dd = ty + i*8;
    VT[((long)b*HDIM + d0 + dd)*SEQ + s0 + tx] = t[tx][dd];
  }
}

// =================== fused scores + softmax + PV ===================
// R21-proven structure; single change: V loads hoisted to loop top (before QKT)
// for extra latency cover. Ledger identical (V remains newest-2 at the vmcnt(2)).
__global__ __launch_bounds__(512, 4)
void k_fused(const unsigned short* __restrict__ Qb, const unsigned short* __restrict__ Kb,
             const unsigned short* __restrict__ VT, float* __restrict__ S,
             unsigned short* __restrict__ AOb){
  int bh = blockIdx.x, b = bh >> 3, h = bh & 7;
  int y = (int)blockIdx.y;
  int ss = (y < 16) ? (31 - y) : (y - 16);    // balanced: pair sums constant
  int qbase = ss * 64;
  int T = 2 * (ss + 1);                       // 32-col k-tiles (>= 2)

  float* Sh = S + (long)bh * SEQ * SEQ;
  const unsigned short* Qh = Qb + (long)b*SEQ*HID + (long)h*HDIM;
  const unsigned short* Kh = Kb + (long)b*SEQ*HDIM;
  const unsigned short* Vh = VT + (long)b*HDIM*SEQ;

  __shared__ unsigned short lK[2][32*256];    // 2 x 16 KB, 512B rows, XOR-swizzled
  __shared__ __bf16 lA[2][64*40];             // 2 x 5 KB E tile, 80B row stride
  __shared__ float lWl[8][64];
  __shared__ float mli[64];

  int tid = threadIdx.x, lane = tid & 63, w = tid >> 6;
  int wr = w >> 1, wc = w & 1;

#define STAGE_K(kt_, buf_)                                                      \
  { _Pragma("unroll")                                                           \
    for (int t = 0; t < 2; ++t){                                                \
      int seg = w*2 + t;                                                        \
      int row = seg*2 + (lane >> 5);                                            \
      int cb  = ((lane & 31)*16) ^ ((row & 7) << 4);                            \
      gload16(Kh + (long)((kt_)*32 + row)*HDIM + (cb >> 1),                     \
              (char*)lK[buf_] + seg*1024);                                      \
    } }

#define QKT(buf_)                                                               \
  { _Pragma("unroll")                                                           \
    for (int kk = 0; kk < 8; ++kk){                                             \
      int rk = wc*16 + (lane & 15);                                             \
      bf16x8 bk = *(const bf16x8*)((const char*)lK[buf_] + rk*512 +             \
                   ((kk*64 + (lane >> 4)*16) ^ ((rk & 7) << 4)));               \
      accs = __builtin_amdgcn_mfma_f32_16x16x32_bf16(aq[kk], bk, accs, 0, 0, 0);\
    } }

  // ---- Q fragments into registers (once; reused in both sweeps) ----
  bf16x8 aq[8];
  {
    const unsigned short* qrow = Qh + (long)(qbase + wr*16 + (lane & 15))*HID + (lane >> 4)*8;
    #pragma unroll
    for (int kk = 0; kk < 8; ++kk)
      aq[kk] = *(const bf16x8*)(qrow + kk*32);
  }

  f32x4 accs;
  f32x4 acc_o[4][2];
  float oL[4];
  #pragma unroll
  for (int q = 0; q < 4; ++q){ accs[q] = 0.f; oL[q] = 0.f; }
  #pragma unroll
  for (int m = 0; m < 4; ++m)
    #pragma unroll
    for (int n = 0; n < 2; ++n)
      #pragma unroll
      for (int q = 0; q < 4; ++q) acc_o[m][n][q] = 0.f;

  // ---------------- sweep 1: l-sums + unnormalized PV ----------------
  STAGE_K(0, 0)
  STAGE_K(1, 1)
  asm volatile("s_waitcnt vmcnt(2)" ::: "memory");
  __builtin_amdgcn_s_barrier();
  for (int kt = 0; kt < T; ++kt){
    // V for this tile: issued at loop top -> QKT+exp cover its latency.
    bf16x8 vf0 = *(const bf16x8*)(Vh + (long)(w*32 +      (lane & 15))*SEQ + kt*32 + (lane >> 4)*8);
    bf16x8 vf1 = *(const bf16x8*)(Vh + (long)(w*32 + 16 + (lane & 15))*SEQ + kt*32 + (lane >> 4)*8);
    __builtin_amdgcn_s_setprio(1);
    QKT(kt & 1)
    __builtin_amdgcn_s_setprio(0);
    if (kt*32 + wc*16 + 15 <= qbase + wr*16){      // wave-uniform: fully valid
      #pragma unroll
      for (int ri = 0; ri < 4; ++ri){
        int rowl = wr*16 + (lane >> 4)*4 + ri;
        int coll = wc*16 + (lane & 15);
        float e = __expf(accs[ri]*0.0625f - 8.0f);
        oL[ri] += e;
        lA[kt & 1][rowl*40 + coll] = (__bf16)e;
        accs[ri] = 0.f;
      }
    } else {
      #pragma unroll
      for (int ri = 0; ri < 4; ++ri){
        int rowl = wr*16 + (lane >> 4)*4 + ri;
        int coll = wc*16 + (lane & 15);
        float e = (kt*32 + coll <= qbase + rowl) ? __expf(accs[ri]*0.0625f - 8.0f) : 0.f;
        oL[ri] += e;
        lA[kt & 1][rowl*40 + coll] = (__bf16)e;
        accs[ri] = 0.f;
      }
    }
    asm volatile("s_waitcnt lgkmcnt(0)" ::: "memory");
    // newest-2 = {V(kt)} -> K(kt+1) retired (ledger identical to R21)
    asm volatile("s_waitcnt vmcnt(2)" ::: "memory");
    __builtin_amdgcn_s_barrier();
    if (kt + 2 < T) STAGE_K(kt + 2, kt & 1)
    __builtin_amdgcn_s_setprio(1);
    #pragma unroll
    for (int m2 = 0; m2 < 4; ++m2){
      int rq = m2*16 + (lane & 15);
      bf16x8 ap = *(const bf16x8*)&lA[kt & 1][rq*40 + (lane >> 4)*8];
      acc_o[m2][0] = __builtin_amdgcn_mfma_f32_16x16x32_bf16(ap, vf0, acc_o[m2][0], 0, 0, 0);
      acc_o[m2][1] = __builtin_amdgcn_mfma_f32_16x16x32_bf16(ap, vf1, acc_o[m2][1], 0, 0, 0);
    }
    __builtin_amdgcn_s_setprio(0);
  }

  // ---------------- l reduce -> mli ----------------
  #pragma unroll
  for (int ri = 0; ri < 4; ++ri){
    float v = oL[ri];
    #pragma unroll
    for (int off = 1; off < 16; off <<= 1) v += __shfl_xor(v, off);
    if ((lane & 15) == 0)
      lWl[w][wr*16 + (lane >> 4)*4 + ri] = v;
  }
  __syncthreads();
  if (tid < 64){
    int g = (tid >> 4) * 2;
    mli[tid] = 1.0f / (lWl[g][tid] + lWl[g+1][tid]);
  }
  __syncthreads();

  float ils[4];
  #pragma unroll
  for (int ri = 0; ri < 4; ++ri)
    ils[ri] = mli[wr*16 + (lane >> 4)*4 + ri];

  // ---------------- O epilogue: AO = (E@V) * il ----------------
  #pragma unroll
  for (int m2 = 0; m2 < 4; ++m2){
    #pragma unroll
    for (int ri = 0; ri < 4; ++ri){
      int row = m2*16 + (lane >> 4)*4 + ri;
      float il = mli[row];
      long gr = (long)b*SEQ + qbase + row;
      #pragma unroll
      for (int n = 0; n < 2; ++n){
        int col = w*32 + n*16 + (lane & 15);
        AOb[gr*HID + h*HDIM + col] = f2bf(acc_o[m2][n][ri] * il);
      }
    }
  }

  // ---------------- sweep 2: recompute + write P directly ----------------
  STAGE_K(0, 0)
  STAGE_K(1, 1)
  asm volatile("s_waitcnt vmcnt(2)" ::: "memory");
  __builtin_amdgcn_s_barrier();
  for (int kt = 0; kt < T; ++kt){
    __builtin_amdgcn_s_setprio(1);
    QKT(kt & 1)
    __builtin_amdgcn_s_setprio(0);
    if (kt*32 + wc*16 + 15 <= qbase + wr*16){      // wave-uniform: fully valid
      #pragma unroll
      for (int ri = 0; ri < 4; ++ri){
        int rowl = wr*16 + (lane >> 4)*4 + ri;
        int coll = wc*16 + (lane & 15);
        Sh[(long)(qbase + rowl)*SEQ + kt*32 + coll] =
            __expf(accs[ri]*0.0625f - 8.0f) * ils[ri];
        accs[ri] = 0.f;
      }
    } else {
      #pragma unroll
      for (int ri = 0; ri < 4; ++ri){
        int rowl = wr*16 + (lane >> 4)*4 + ri;
        int coll = wc*16 + (lane & 15);
        float p = (kt*32 + coll <= qbase + rowl)
                  ? __expf(accs[ri]*0.0625f - 8.0f) * ils[ri] : 0.f;
        Sh[(long)(qbase + rowl)*SEQ + kt*32 + coll] = p;
        accs[ri] = 0.f;
      }
    }
    asm volatile("s_waitcnt vmcnt(4)" ::: "memory");
    __builtin_amdgcn_s_barrier();
    if (kt + 2 < T) STAGE_K(kt + 2, kt & 1)
  }

  // ---------------- zero tail ----------------
  {
    f32x4 z4; z4[0]=0.f; z4[1]=0.f; z4[2]=0.f; z4[3]=0.f;
    int row = qbase + (tid >> 3);
    for (int c = T*32 + (tid & 7)*4; c < SEQ; c += 32)
      *(f32x4*)&Sh[(long)row*SEQ + c] = z4;
  }
#undef STAGE_K
#undef QKT
}

// ---- 256x128 deep-pipelined GEMM (8 waves, BK=64, dbuf LDS, counted vmcnt) ----
// (R11/R16 version — proven best)
template<int OUTF32>
__global__ __launch_bounds__(512, 1)
void gemm256(const unsigned short* __restrict__ A16, const unsigned short* __restrict__ BT,
             void* __restrict__ Cv, int lda, int ldb, int ldc, int K){
  constexpr int BM = 256, BN = 128, BK = 64;
  int m0 = blockIdx.x * BM, n0 = blockIdx.y * BN;

  __shared__ unsigned short lA[2][BM*BK];
  __shared__ unsigned short lB[2][BN*BK];

  int tid = threadIdx.x, lane = tid & 63, w = tid >> 6;
  int wr = w >> 1, wc = w & 1;
  int srow = lane >> 3;
  int vswz = ((lane & 7) ^ ((lane >> 3) & 7)) * 8;

  f32x4 acc[4][4];
  #pragma unroll
  for (int m = 0; m < 4; ++m)
    #pragma unroll
    for (int n = 0; n < 4; ++n)
      #pragma unroll
      for (int q = 0; q < 4; ++q) acc[m][n][q] = 0.f;

  int NT = K / BK;

#define STAGE256(kt_, buf_)                                                    \
  { int k0_ = (kt_) * BK;                                                      \
    _Pragma("unroll")                                                          \
    for (int t = 0; t < 4; ++t){                                               \
      int seg = w*4 + t;                                                       \
      const unsigned short* src = A16 + (long)(m0 + seg*8 + srow)*lda + k0_ + vswz; \
      gload16(src, (char*)lA[buf_] + seg*1024);                                \
    }                                                                          \
    _Pragma("unroll")                                                          \
    for (int t = 0; t < 2; ++t){                                               \
      int seg = w*2 + t;                                                       \
      const unsigned short* src = BT + (long)(n0 + seg*8 + srow)*ldb + k0_ + vswz; \
      gload16(src, (char*)lB[buf_] + seg*1024);                                \
    } }

  STAGE256(0, 0)
  STAGE256(1, 1)
  int cur = 0;

  for (int kt = 0; kt < NT; ++kt){
    if (kt < NT - 1) asm volatile("s_waitcnt vmcnt(6)" ::: "memory");
    else             asm volatile("s_waitcnt vmcnt(0)" ::: "memory");
    __builtin_amdgcn_s_barrier();

    const char* La = (const char*)lA[cur];
    const char* Lb = (const char*)lB[cur];
    __builtin_amdgcn_s_setprio(1);
    #pragma unroll
    for (int kk = 0; kk < 2; ++kk){
      bf16x8 af[4], bfr[4];
      #pragma unroll
      for (int m = 0; m < 4; ++m){
        int row = wr*64 + m*16 + (lane & 15);
        int kb = (kk*64 + (lane >> 4)*16) ^ ((row & 7) << 4);
        af[m] = *(const bf16x8*)(La + row*128 + kb);
      }
      #pragma unroll
      for (int n = 0; n < 4; ++n){
        int row = wc*64 + n*16 + (lane & 15);
        int kb = (kk*64 + (lane >> 4)*16) ^ ((row & 7) << 4);
        bfr[n] = *(const bf16x8*)(Lb + row*128 + kb);
      }
      #pragma unroll
      for (int m = 0; m < 4; ++m)
        #pragma unroll
        for (int n = 0; n < 4; ++n)
          acc[m][n] = __builtin_amdgcn_mfma_f32_16x16x32_bf16(af[m], bfr[n], acc[m][n], 0, 0, 0);
    }
    __builtin_amdgcn_s_setprio(0);
    __builtin_amdgcn_s_barrier();
    if (kt + 2 < NT) STAGE256(kt + 2, cur)
    cur ^= 1;
  }
#undef STAGE256

  #pragma unroll
  for (int m = 0; m < 4; ++m){
    #pragma unroll
    for (int ri = 0; ri < 4; ++ri){
      int orow = m0 + wr*64 + m*16 + (lane >> 4)*4 + ri;
      #pragma unroll
      for (int n = 0; n < 4; ++n){
        int ocol = n0 + wc*64 + n*16 + (lane & 15);
        float vv = acc[m][n][ri];
        if (OUTF32) ((float*)Cv)[(long)orow*ldc + ocol] = vv;
        else        ((unsigned short*)Cv)[(long)orow*ldc + ocol] = f2bf(vv);
      }
    }
  }
}

extern "C" void kernel_launch(void* const* d_in, const int* in_sizes, int n_in,
                              void* d_out, int out_size, void* d_ws, size_t ws_size,
                              hipStream_t stream){
  const float* hs  = (const float*)d_in[0];
  const int*   pos = (const int*)  d_in[1];
  const float* Wq  = (const float*)d_in[3];
  const float* Wk  = (const float*)d_in[4];
  const float* Wv  = (const float*)d_in[5];
  const float* Wo  = (const float*)d_in[6];

  float* out  = (float*)d_out;
  float* Sbuf = out + (long)ROWS * HID;

  unsigned short* wsp   = (unsigned short*)d_ws;
  unsigned short* hsb   = wsp;
  unsigned short* wqkvT = hsb   + (long)ROWS*HID;
  unsigned short* woT   = wqkvT + (long)QKVN*HID;
  unsigned short* qkvb  = woT   + (long)HID*HID;
  unsigned short* Qb    = qkvb  + (long)ROWS*QKVN;
  unsigned short* Kb    = Qb    + (long)ROWS*HID;
  unsigned short* VT    = Kb    + (long)ROWS*HDIM;
  unsigned short* AOb   = VT    + (long)BATCH*HDIM*SEQ;

  // 1. hs convert + all weight transposes (one dispatch)
  k_prep<<<2048 + 9216, 256, 0, stream>>>(hs, hsb, Wq, Wk, Wv, Wo, wqkvT, woT);

  // 2. QKV projection
  gemm256<0><<<dim3(ROWS/256, QKVN/128), 512, 0, stream>>>(
      hsb, wqkvT, qkvb, HID, HID, QKVN, HID);

  // 3. RoPE (Q,K) + V transpose (one dispatch)
  k_mid<<<ROWS + 1024, 256, 0, stream>>>(qkvb, pos, Qb, Kb, VT);

  // 4. fused scores + softmax + PV (S written once, never re-read)
  k_fused<<<dim3(NBH, 32), 512, 0, stream>>>(Qb, Kb, VT, Sbuf, AOb);

  // 5. out = attn_out @ Wo
  gemm256<1><<<dim3(ROWS/256, HID/128), 512, 0, stream>>>(
      AOb, woT, out, HID, HID, HID, HID);
}

// Round 25
// 302.622 us; speedup vs baseline: 1.0220x; 1.0220x over previous
//
#include <hip/hip_runtime.h>
#include <hip/hip_bf16.h>
#include <math.h>

typedef __attribute__((ext_vector_type(4))) float f32x4;
typedef __attribute__((ext_vector_type(8))) __bf16 bf16x8;
typedef __attribute__((ext_vector_type(8))) unsigned short u16x8;

#define HID    2048
#define NHEADS 8
#define HDIM   256
#define SEQ    2048
#define BATCH  2
#define ROWS   (BATCH*SEQ)                 // 4096
#define QKVN   (NHEADS*HDIM + 2*HDIM)      // 2560
#define NBH    (BATCH*NHEADS)              // 16

typedef __attribute__((address_space(1))) const void gvoid_t;
typedef __attribute__((address_space(3))) void lvoid_t;

__device__ __forceinline__ void gload16(const void* g, void* l){
  __builtin_amdgcn_global_load_lds((gvoid_t*)g, (lvoid_t*)l, 16, 0, 0);
}

__device__ __forceinline__ float bf2f(unsigned short u){
  union { unsigned int i; float f; } x; x.i = ((unsigned int)u) << 16; return x.f;
}
__device__ __forceinline__ unsigned short f2bf(float f){
  union { float f; unsigned int i; } x; x.f = f;
  unsigned int u = x.i;
  return (unsigned short)((u + 0x7FFFu + ((u >> 16) & 1u)) >> 16);
}

// ============ k_prep: hs f32->bf16 convert (blocks 0..2047) ============
// ============         + batched weight transposes (blocks 2048..11263) ============
__global__ __launch_bounds__(256)
void k_prep(const float* __restrict__ hs, unsigned short* __restrict__ hsb,
            const float* __restrict__ Wq, const float* __restrict__ Wk,
            const float* __restrict__ Wv, const float* __restrict__ Wo,
            unsigned short* __restrict__ wqkvT, unsigned short* __restrict__ woT){
  int bid = (int)blockIdx.x;
  if (bid < 2048){
    long i = ((long)bid * 256 + threadIdx.x) * 16;
    f32x4 x0 = *(const f32x4*)(hs + i);
    f32x4 x1 = *(const f32x4*)(hs + i + 4);
    f32x4 x2 = *(const f32x4*)(hs + i + 8);
    f32x4 x3 = *(const f32x4*)(hs + i + 12);
    u16x8 w0, w1;
    #pragma unroll
    for (int j = 0; j < 4; ++j){
      w0[j]   = f2bf(x0[j]);
      w0[4+j] = f2bf(x1[j]);
      w1[j]   = f2bf(x2[j]);
      w1[4+j] = f2bf(x3[j]);
    }
    *(u16x8*)(hsb + i)     = w0;
    *(u16x8*)(hsb + i + 8) = w1;
    return;
  }
  // ---- weight transpose: f32 (2048 x srcCols) -> bf16 (srcCols x 2048) ----
  __shared__ float t[32][33];
  bid -= 2048;
  const float* src; unsigned short* dst; int srcCols, gx, local;
  if (bid < 4096)      { src = Wq; dst = wqkvT;                        srcCols = HID;  gx = 64; local = bid; }
  else if (bid < 4608) { src = Wk; dst = wqkvT + (long)HID*HID;        srcCols = HDIM; gx = 8;  local = bid - 4096; }
  else if (bid < 5120) { src = Wv; dst = wqkvT + (long)(HID+HDIM)*HID; srcCols = HDIM; gx = 8;  local = bid - 4608; }
  else                 { src = Wo; dst = woT;                          srcCols = HID;  gx = 64; local = bid - 5120; }
  int bx = (local % gx) * 32;
  int by = (local / gx) * 32;
  int tx = threadIdx.x & 31, ty = threadIdx.x >> 5;
  #pragma unroll
  for (int i = 0; i < 4; ++i){
    int rr = ty + i*8;
    t[rr][tx] = src[(long)(by + rr)*srcCols + bx + tx];
  }
  __syncthreads();
  #pragma unroll
  for (int i = 0; i < 4; ++i){
    int rr = ty + i*8;
    dst[(long)(bx + rr)*HID + by + tx] = f2bf(t[tx][rr]);
  }
}

// ============ k_mid: RoPE Q/K (blocks 0..4095) + V transpose (blocks 4096..5119) ============
__global__ __launch_bounds__(256)
void k_mid(const unsigned short* __restrict__ qkv, const int* __restrict__ pos_ids,
           unsigned short* __restrict__ Qb, unsigned short* __restrict__ Kb,
           unsigned short* __restrict__ VT){
  int bid = (int)blockIdx.x;
  int tid = threadIdx.x;
  if (bid < ROWS){
    int row = bid;
    float pos = (float)pos_ids[row];
    const unsigned short* r = qkv + (long)row * QKVN;
    #pragma unroll
    for (int it = 0; it < 4; ++it){
      int p = it*256 + tid;
      int d = p & 127, h = p >> 7;
      int col = h*HDIM + d;
      float inv = exp2f((float)d * -0.10381025296523132f);
      float ang = pos * inv;
      float sn, cs; sincosf(ang, &sn, &cs);
      float x0 = bf2f(r[col]), x1 = bf2f(r[col + 128]);
      Qb[(long)row*HID + col]       = f2bf(x0*cs - x1*sn);
      Qb[(long)row*HID + col + 128] = f2bf(x1*cs + x0*sn);
    }
    if (tid < 128){
      int d = tid;
      float inv = exp2f((float)d * -0.10381025296523132f);
      float ang = pos * inv;
      float sn, cs; sincosf(ang, &sn, &cs);
      float x0 = bf2f(r[HID + d]), x1 = bf2f(r[HID + d + 128]);
      Kb[(long)row*HDIM + d]       = f2bf(x0*cs - x1*sn);
      Kb[(long)row*HDIM + d + 128] = f2bf(x1*cs + x0*sn);
    }
    return;
  }
  __shared__ unsigned short t[32][34];
  int local = bid - ROWS;
  int b  = local >> 9;
  int rem = local & 511;
  int s0 = (rem >> 3) * 32;
  int d0 = (rem & 7) * 32;
  int tx = tid & 31, ty = tid >> 5;
  #pragma unroll
  for (int i = 0; i < 4; ++i){
    int rr = ty + i*8;
    t[rr][tx] = qkv[(long)(b*SEQ + s0 + rr)*QKVN + HID + HDIM + d0 + tx];
  }
  __syncthreads();
  #pragma unroll
  for (int i = 0; i < 4; ++i){
    int dd = ty + i*8;
    VT[((long)b*HDIM + d0 + dd)*SEQ + s0 + tx] = t[tx][dd];
  }
}

// =================== fused scores + softmax + PV ===================
// R16-proven structure: Q in registers from Qb, lK dbuf (counted vmcnt),
// lA dbuf -> ONE barrier per tile, fixed-shift softmax e = exp(s-8),
// wave-uniform causal fast path, balanced strip pairing.
__global__ __launch_bounds__(512, 4)
void k_fused(const unsigned short* __restrict__ Qb, const unsigned short* __restrict__ Kb,
             const unsigned short* __restrict__ VT, float* __restrict__ S,
             unsigned short* __restrict__ AOb){
  int bh = blockIdx.x, b = bh >> 3, h = bh & 7;
  int y = (int)blockIdx.y;
  int ss = (y < 16) ? (31 - y) : (y - 16);    // balanced: pair sums constant
  int qbase = ss * 64;
  int T = 2 * (ss + 1);                       // 32-col k-tiles (>= 2)

  float* Sh = S + (long)bh * SEQ * SEQ;
  const unsigned short* Qh = Qb + (long)b*SEQ*HID + (long)h*HDIM;
  const unsigned short* Kh = Kb + (long)b*SEQ*HDIM;
  const unsigned short* Vh = VT + (long)b*HDIM*SEQ;

  __shared__ unsigned short lK[2][32*256];    // 2 x 16 KB, 512B rows, XOR-swizzled
  __shared__ __bf16 lA[2][64*40];             // 2 x 5 KB E tile, 80B row stride
  __shared__ float lWl[8][64];
  __shared__ float mli[64];

  int tid = threadIdx.x, lane = tid & 63, w = tid >> 6;
  int wr = w >> 1, wc = w & 1;

#define STAGE_K(kt_, buf_)                                                      \
  { _Pragma("unroll")                                                           \
    for (int t = 0; t < 2; ++t){                                                \
      int seg = w*2 + t;                                                        \
      int row = seg*2 + (lane >> 5);                                            \
      int cb  = ((lane & 31)*16) ^ ((row & 7) << 4);                            \
      gload16(Kh + (long)((kt_)*32 + row)*HDIM + (cb >> 1),                     \
              (char*)lK[buf_] + seg*1024);                                      \
    } }

#define QKT(buf_)                                                               \
  { _Pragma("unroll")                                                           \
    for (int kk = 0; kk < 8; ++kk){                                             \
      int rk = wc*16 + (lane & 15);                                             \
      bf16x8 bk = *(const bf16x8*)((const char*)lK[buf_] + rk*512 +             \
                   ((kk*64 + (lane >> 4)*16) ^ ((rk & 7) << 4)));               \
      accs = __builtin_amdgcn_mfma_f32_16x16x32_bf16(aq[kk], bk, accs, 0, 0, 0);\
    } }

  // ---- Q fragments into registers (once; reused in both sweeps) ----
  bf16x8 aq[8];
  {
    const unsigned short* qrow = Qh + (long)(qbase + wr*16 + (lane & 15))*HID + (lane >> 4)*8;
    #pragma unroll
    for (int kk = 0; kk < 8; ++kk)
      aq[kk] = *(const bf16x8*)(qrow + kk*32);
  }

  f32x4 accs;
  f32x4 acc_o[4][2];
  float oL[4];
  #pragma unroll
  for (int q = 0; q < 4; ++q){ accs[q] = 0.f; oL[q] = 0.f; }
  #pragma unroll
  for (int m = 0; m < 4; ++m)
    #pragma unroll
    for (int n = 0; n < 2; ++n)
      #pragma unroll
      for (int q = 0; q < 4; ++q) acc_o[m][n][q] = 0.f;

  // ---------------- sweep 1: l-sums + unnormalized PV ----------------
  STAGE_K(0, 0)
  STAGE_K(1, 1)
  asm volatile("s_waitcnt vmcnt(2)" ::: "memory");
  __builtin_amdgcn_s_barrier();
  for (int kt = 0; kt < T; ++kt){
    __builtin_amdgcn_s_setprio(1);
    QKT(kt & 1)
    __builtin_amdgcn_s_setprio(0);
    if (kt*32 + wc*16 + 15 <= qbase + wr*16){      // wave-uniform: fully valid
      #pragma unroll
      for (int ri = 0; ri < 4; ++ri){
        int rowl = wr*16 + (lane >> 4)*4 + ri;
        int coll = wc*16 + (lane & 15);
        float e = __expf(accs[ri]*0.0625f - 8.0f);
        oL[ri] += e;
        lA[kt & 1][rowl*40 + coll] = (__bf16)e;
        accs[ri] = 0.f;
      }
    } else {
      #pragma unroll
      for (int ri = 0; ri < 4; ++ri){
        int rowl = wr*16 + (lane >> 4)*4 + ri;
        int coll = wc*16 + (lane & 15);
        float e = (kt*32 + coll <= qbase + rowl) ? __expf(accs[ri]*0.0625f - 8.0f) : 0.f;
        oL[ri] += e;
        lA[kt & 1][rowl*40 + coll] = (__bf16)e;
        accs[ri] = 0.f;
      }
    }
    bf16x8 vf0 = *(const bf16x8*)(Vh + (long)(w*32 +      (lane & 15))*SEQ + kt*32 + (lane >> 4)*8);
    bf16x8 vf1 = *(const bf16x8*)(Vh + (long)(w*32 + 16 + (lane & 15))*SEQ + kt*32 + (lane >> 4)*8);
    asm volatile("s_waitcnt lgkmcnt(0)" ::: "memory");
    asm volatile("s_waitcnt vmcnt(2)" ::: "memory");
    __builtin_amdgcn_s_barrier();
    if (kt + 2 < T) STAGE_K(kt + 2, kt & 1)
    __builtin_amdgcn_s_setprio(1);
    #pragma unroll
    for (int m2 = 0; m2 < 4; ++m2){
      int rq = m2*16 + (lane & 15);
      bf16x8 ap = *(const bf16x8*)&lA[kt & 1][rq*40 + (lane >> 4)*8];
      acc_o[m2][0] = __builtin_amdgcn_mfma_f32_16x16x32_bf16(ap, vf0, acc_o[m2][0], 0, 0, 0);
      acc_o[m2][1] = __builtin_amdgcn_mfma_f32_16x16x32_bf16(ap, vf1, acc_o[m2][1], 0, 0, 0);
    }
    __builtin_amdgcn_s_setprio(0);
  }

  // ---------------- l reduce -> mli ----------------
  #pragma unroll
  for (int ri = 0; ri < 4; ++ri){
    float v = oL[ri];
    #pragma unroll
    for (int off = 1; off < 16; off <<= 1) v += __shfl_xor(v, off);
    if ((lane & 15) == 0)
      lWl[w][wr*16 + (lane >> 4)*4 + ri] = v;
  }
  __syncthreads();
  if (tid < 64){
    int g = (tid >> 4) * 2;
    mli[tid] = 1.0f / (lWl[g][tid] + lWl[g+1][tid]);
  }
  __syncthreads();

  float ils[4];
  #pragma unroll
  for (int ri = 0; ri < 4; ++ri)
    ils[ri] = mli[wr*16 + (lane >> 4)*4 + ri];

  // ---------------- O epilogue: AO = (E@V) * il ----------------
  #pragma unroll
  for (int m2 = 0; m2 < 4; ++m2){
    #pragma unroll
    for (int ri = 0; ri < 4; ++ri){
      int row = m2*16 + (lane >> 4)*4 + ri;
      float il = mli[row];
      long gr = (long)b*SEQ + qbase + row;
      #pragma unroll
      for (int n = 0; n < 2; ++n){
        int col = w*32 + n*16 + (lane & 15);
        AOb[gr*HID + h*HDIM + col] = f2bf(acc_o[m2][n][ri] * il);
      }
    }
  }

  // ---------------- sweep 2: recompute + write P directly ----------------
  STAGE_K(0, 0)
  STAGE_K(1, 1)
  asm volatile("s_waitcnt vmcnt(2)" ::: "memory");
  __builtin_amdgcn_s_barrier();
  for (int kt = 0; kt < T; ++kt){
    __builtin_amdgcn_s_setprio(1);
    QKT(kt & 1)
    __builtin_amdgcn_s_setprio(0);
    if (kt*32 + wc*16 + 15 <= qbase + wr*16){      // wave-uniform: fully valid
      #pragma unroll
      for (int ri = 0; ri < 4; ++ri){
        int rowl = wr*16 + (lane >> 4)*4 + ri;
        int coll = wc*16 + (lane & 15);
        Sh[(long)(qbase + rowl)*SEQ + kt*32 + coll] =
            __expf(accs[ri]*0.0625f - 8.0f) * ils[ri];
        accs[ri] = 0.f;
      }
    } else {
      #pragma unroll
      for (int ri = 0; ri < 4; ++ri){
        int rowl = wr*16 + (lane >> 4)*4 + ri;
        int coll = wc*16 + (lane & 15);
        float p = (kt*32 + coll <= qbase + rowl)
                  ? __expf(accs[ri]*0.0625f - 8.0f) * ils[ri] : 0.f;
        Sh[(long)(qbase + rowl)*SEQ + kt*32 + coll] = p;
        accs[ri] = 0.f;
      }
    }
    asm volatile("s_waitcnt vmcnt(4)" ::: "memory");
    __builtin_amdgcn_s_barrier();
    if (kt + 2 < T) STAGE_K(kt + 2, kt & 1)
  }

  // ---------------- zero tail ----------------
  {
    f32x4 z4; z4[0]=0.f; z4[1]=0.f; z4[2]=0.f; z4[3]=0.f;
    int row = qbase + (tid >> 3);
    for (int c = T*32 + (tid & 7)*4; c < SEQ; c += 32)
      *(f32x4*)&Sh[(long)row*SEQ + c] = z4;
  }
#undef STAGE_K
#undef QKT
}

// ---- 256x128 deep-pipelined GEMM (8 waves, BK=64, dbuf LDS, counted vmcnt) ----
// (R11/R16 version — proven best)
template<int OUTF32>
__global__ __launch_bounds__(512, 1)
void gemm256(const unsigned short* __restrict__ A16, const unsigned short* __restrict__ BT,
             void* __restrict__ Cv, int lda, int ldb, int ldc, int K){
  constexpr int BM = 256, BN = 128, BK = 64;
  int m0 = blockIdx.x * BM, n0 = blockIdx.y * BN;

  __shared__ unsigned short lA[2][BM*BK];
  __shared__ unsigned short lB[2][BN*BK];

  int tid = threadIdx.x, lane = tid & 63, w = tid >> 6;
  int wr = w >> 1, wc = w & 1;
  int srow = lane >> 3;
  int vswz = ((lane & 7) ^ ((lane >> 3) & 7)) * 8;

  f32x4 acc[4][4];
  #pragma unroll
  for (int m = 0; m < 4; ++m)
    #pragma unroll
    for (int n = 0; n < 4; ++n)
      #pragma unroll
      for (int q = 0; q < 4; ++q) acc[m][n][q] = 0.f;

  int NT = K / BK;

#define STAGE256(kt_, buf_)                                                    \
  { int k0_ = (kt_) * BK;                                                      \
    _Pragma("unroll")                                                          \
    for (int t = 0; t < 4; ++t){                                               \
      int seg = w*4 + t;                                                       \
      const unsigned short* src = A16 + (long)(m0 + seg*8 + srow)*lda + k0_ + vswz; \
      gload16(src, (char*)lA[buf_] + seg*1024);                                \
    }                                                                          \
    _Pragma("unroll")                                                          \
    for (int t = 0; t < 2; ++t){                                               \
      int seg = w*2 + t;                                                       \
      const unsigned short* src = BT + (long)(n0 + seg*8 + srow)*ldb + k0_ + vswz; \
      gload16(src, (char*)lB[buf_] + seg*1024);                                \
    } }

  STAGE256(0, 0)
  STAGE256(1, 1)
  int cur = 0;

  for (int kt = 0; kt < NT; ++kt){
    if (kt < NT - 1) asm volatile("s_waitcnt vmcnt(6)" ::: "memory");
    else             asm volatile("s_waitcnt vmcnt(0)" ::: "memory");
    __builtin_amdgcn_s_barrier();

    const char* La = (const char*)lA[cur];
    const char* Lb = (const char*)lB[cur];
    __builtin_amdgcn_s_setprio(1);
    #pragma unroll
    for (int kk = 0; kk < 2; ++kk){
      bf16x8 af[4], bfr[4];
      #pragma unroll
      for (int m = 0; m < 4; ++m){
        int row = wr*64 + m*16 + (lane & 15);
        int kb = (kk*64 + (lane >> 4)*16) ^ ((row & 7) << 4);
        af[m] = *(const bf16x8*)(La + row*128 + kb);
      }
      #pragma unroll
      for (int n = 0; n < 4; ++n){
        int row = wc*64 + n*16 + (lane & 15);
        int kb = (kk*64 + (lane >> 4)*16) ^ ((row & 7) << 4);
        bfr[n] = *(const bf16x8*)(Lb + row*128 + kb);
      }
      #pragma unroll
      for (int m = 0; m < 4; ++m)
        #pragma unroll
        for (int n = 0; n < 4; ++n)
          acc[m][n] = __builtin_amdgcn_mfma_f32_16x16x32_bf16(af[m], bfr[n], acc[m][n], 0, 0, 0);
    }
    __builtin_amdgcn_s_setprio(0);
    __builtin_amdgcn_s_barrier();
    if (kt + 2 < NT) STAGE256(kt + 2, cur)
    cur ^= 1;
  }
#undef STAGE256

  #pragma unroll
  for (int m = 0; m < 4; ++m){
    #pragma unroll
    for (int ri = 0; ri < 4; ++ri){
      int orow = m0 + wr*64 + m*16 + (lane >> 4)*4 + ri;
      #pragma unroll
      for (int n = 0; n < 4; ++n){
        int ocol = n0 + wc*64 + n*16 + (lane & 15);
        float vv = acc[m][n][ri];
        if (OUTF32) ((float*)Cv)[(long)orow*ldc + ocol] = vv;
        else        ((unsigned short*)Cv)[(long)orow*ldc + ocol] = f2bf(vv);
      }
    }
  }
}

extern "C" void kernel_launch(void* const* d_in, const int* in_sizes, int n_in,
                              void* d_out, int out_size, void* d_ws, size_t ws_size,
                              hipStream_t stream){
  const float* hs  = (const float*)d_in[0];
  const int*   pos = (const int*)  d_in[1];
  const float* Wq  = (const float*)d_in[3];
  const float* Wk  = (const float*)d_in[4];
  const float* Wv  = (const float*)d_in[5];
  const float* Wo  = (const float*)d_in[6];

  float* out  = (float*)d_out;
  float* Sbuf = out + (long)ROWS * HID;

  unsigned short* wsp   = (unsigned short*)d_ws;
  unsigned short* hsb   = wsp;
  unsigned short* wqkvT = hsb   + (long)ROWS*HID;
  unsigned short* woT   = wqkvT + (long)QKVN*HID;
  unsigned short* qkvb  = woT   + (long)HID*HID;
  unsigned short* Qb    = qkvb  + (long)ROWS*QKVN;
  unsigned short* Kb    = Qb    + (long)ROWS*HID;
  unsigned short* VT    = Kb    + (long)ROWS*HDIM;
  unsigned short* AOb   = VT    + (long)BATCH*HDIM*SEQ;

  // 1. hs convert + all weight transposes (one dispatch)
  k_prep<<<2048 + 9216, 256, 0, stream>>>(hs, hsb, Wq, Wk, Wv, Wo, wqkvT, woT);

  // 2. QKV projection
  gemm256<0><<<dim3(ROWS/256, QKVN/128), 512, 0, stream>>>(
      hsb, wqkvT, qkvb, HID, HID, QKVN, HID);

  // 3. RoPE (Q,K) + V transpose (one dispatch)
  k_mid<<<ROWS + 1024, 256, 0, stream>>>(qkvb, pos, Qb, Kb, VT);

  // 4. fused scores + softmax + PV (S written once, never re-read)
  k_fused<<<dim3(NBH, 32), 512, 0, stream>>>(Qb, Kb, VT, Sbuf, AOb);

  // 5. out = attn_out @ Wo
  gemm256<1><<<dim3(ROWS/256, HID/128), 512, 0, stream>>>(
      AOb, woT, out, HID, HID, HID, HID);
}

// Round 26
// 301.268 us; speedup vs baseline: 1.0266x; 1.0045x over previous
//
#include <hip/hip_runtime.h>
#include <hip/hip_bf16.h>
#include <math.h>

typedef __attribute__((ext_vector_type(4))) float f32x4;
typedef __attribute__((ext_vector_type(8))) __bf16 bf16x8;
typedef __attribute__((ext_vector_type(8))) unsigned short u16x8;

#define HID    2048
#define NHEADS 8
#define HDIM   256
#define SEQ    2048
#define BATCH  2
#define ROWS   (BATCH*SEQ)                 // 4096
#define QKVN   (NHEADS*HDIM + 2*HDIM)      // 2560
#define NBH    (BATCH*NHEADS)              // 16

typedef __attribute__((address_space(1))) const void gvoid_t;
typedef __attribute__((address_space(3))) void lvoid_t;

__device__ __forceinline__ void gload16(const void* g, void* l){
  __builtin_amdgcn_global_load_lds((gvoid_t*)g, (lvoid_t*)l, 16, 0, 0);
}

__device__ __forceinline__ float bf2f(unsigned short u){
  union { unsigned int i; float f; } x; x.i = ((unsigned int)u) << 16; return x.f;
}
__device__ __forceinline__ unsigned short f2bf(float f){
  union { float f; unsigned int i; } x; x.f = f;
  unsigned int u = x.i;
  return (unsigned short)((u + 0x7FFFu + ((u >> 16) & 1u)) >> 16);
}

// ============ k_prep: hs f32->bf16 convert (blocks 0..2047) ============
// ============         + batched weight transposes (blocks 2048..11263) ============
__global__ __launch_bounds__(256)
void k_prep(const float* __restrict__ hs, unsigned short* __restrict__ hsb,
            const float* __restrict__ Wq, const float* __restrict__ Wk,
            const float* __restrict__ Wv, const float* __restrict__ Wo,
            unsigned short* __restrict__ wqkvT, unsigned short* __restrict__ woT){
  int bid = (int)blockIdx.x;
  if (bid < 2048){
    long i = ((long)bid * 256 + threadIdx.x) * 16;
    f32x4 x0 = *(const f32x4*)(hs + i);
    f32x4 x1 = *(const f32x4*)(hs + i + 4);
    f32x4 x2 = *(const f32x4*)(hs + i + 8);
    f32x4 x3 = *(const f32x4*)(hs + i + 12);
    u16x8 w0, w1;
    #pragma unroll
    for (int j = 0; j < 4; ++j){
      w0[j]   = f2bf(x0[j]);
      w0[4+j] = f2bf(x1[j]);
      w1[j]   = f2bf(x2[j]);
      w1[4+j] = f2bf(x3[j]);
    }
    *(u16x8*)(hsb + i)     = w0;
    *(u16x8*)(hsb + i + 8) = w1;
    return;
  }
  // ---- weight transpose: f32 (2048 x srcCols) -> bf16 (srcCols x 2048) ----
  __shared__ float t[32][33];
  bid -= 2048;
  const float* src; unsigned short* dst; int srcCols, gx, local;
  if (bid < 4096)      { src = Wq; dst = wqkvT;                        srcCols = HID;  gx = 64; local = bid; }
  else if (bid < 4608) { src = Wk; dst = wqkvT + (long)HID*HID;        srcCols = HDIM; gx = 8;  local = bid - 4096; }
  else if (bid < 5120) { src = Wv; dst = wqkvT + (long)(HID+HDIM)*HID; srcCols = HDIM; gx = 8;  local = bid - 4608; }
  else                 { src = Wo; dst = woT;                          srcCols = HID;  gx = 64; local = bid - 5120; }
  int bx = (local % gx) * 32;
  int by = (local / gx) * 32;
  int tx = threadIdx.x & 31, ty = threadIdx.x >> 5;
  #pragma unroll
  for (int i = 0; i < 4; ++i){
    int rr = ty + i*8;
    t[rr][tx] = src[(long)(by + rr)*srcCols + bx + tx];
  }
  __syncthreads();
  #pragma unroll
  for (int i = 0; i < 4; ++i){
    int rr = ty + i*8;
    dst[(long)(bx + rr)*HID + by + tx] = f2bf(t[tx][rr]);
  }
}

// ============ k_mid: RoPE Q/K (blocks 0..4095) + V transpose (blocks 4096..5119) ============
__global__ __launch_bounds__(256)
void k_mid(const unsigned short* __restrict__ qkv, const int* __restrict__ pos_ids,
           unsigned short* __restrict__ Qb, unsigned short* __restrict__ Kb,
           unsigned short* __restrict__ VT){
  int bid = (int)blockIdx.x;
  int tid = threadIdx.x;
  if (bid < ROWS){
    int row = bid;
    float pos = (float)pos_ids[row];
    const unsigned short* r = qkv + (long)row * QKVN;
    #pragma unroll
    for (int it = 0; it < 4; ++it){
      int p = it*256 + tid;
      int d = p & 127, h = p >> 7;
      int col = h*HDIM + d;
      float inv = exp2f((float)d * -0.10381025296523132f);
      float ang = pos * inv;
      float sn, cs; sincosf(ang, &sn, &cs);
      float x0 = bf2f(r[col]), x1 = bf2f(r[col + 128]);
      Qb[(long)row*HID + col]       = f2bf(x0*cs - x1*sn);
      Qb[(long)row*HID + col + 128] = f2bf(x1*cs + x0*sn);
    }
    if (tid < 128){
      int d = tid;
      float inv = exp2f((float)d * -0.10381025296523132f);
      float ang = pos * inv;
      float sn, cs; sincosf(ang, &sn, &cs);
      float x0 = bf2f(r[HID + d]), x1 = bf2f(r[HID + d + 128]);
      Kb[(long)row*HDIM + d]       = f2bf(x0*cs - x1*sn);
      Kb[(long)row*HDIM + d + 128] = f2bf(x1*cs + x0*sn);
    }
    return;
  }
  __shared__ unsigned short t[32][34];
  int local = bid - ROWS;
  int b  = local >> 9;
  int rem = local & 511;
  int s0 = (rem >> 3) * 32;
  int d0 = (rem & 7) * 32;
  int tx = tid & 31, ty = tid >> 5;
  #pragma unroll
  for (int i = 0; i < 4; ++i){
    int rr = ty + i*8;
    t[rr][tx] = qkv[(long)(b*SEQ + s0 + rr)*QKVN + HID + HDIM + d0 + tx];
  }
  __syncthreads();
  #pragma unroll
  for (int i = 0; i < 4; ++i){
    int dd = ty + i*8;
    VT[((long)b*HDIM + d0 + dd)*SEQ + s0 + tx] = t[tx][dd];
  }
}

// =================== fused scores + softmax + PV ===================
// R16-proven structure: Q in registers from Qb, lK dbuf (counted vmcnt),
// lA dbuf -> ONE barrier per tile, fixed-shift softmax e = exp(s-8),
// wave-uniform causal fast path, balanced strip pairing.
__global__ __launch_bounds__(512, 4)
void k_fused(const unsigned short* __restrict__ Qb, const unsigned short* __restrict__ Kb,
             const unsigned short* __restrict__ VT, float* __restrict__ S,
             unsigned short* __restrict__ AOb){
  int bh = blockIdx.x, b = bh >> 3, h = bh & 7;
  int y = (int)blockIdx.y;
  int ss = (y < 16) ? (31 - y) : (y - 16);    // balanced: pair sums constant
  int qbase = ss * 64;
  int T = 2 * (ss + 1);                       // 32-col k-tiles (>= 2)

  float* Sh = S + (long)bh * SEQ * SEQ;
  const unsigned short* Qh = Qb + (long)b*SEQ*HID + (long)h*HDIM;
  const unsigned short* Kh = Kb + (long)b*SEQ*HDIM;
  const unsigned short* Vh = VT + (long)b*HDIM*SEQ;

  __shared__ unsigned short lK[2][32*256];    // 2 x 16 KB, 512B rows, XOR-swizzled
  __shared__ __bf16 lA[2][64*40];             // 2 x 5 KB E tile, 80B row stride
  __shared__ float lWl[8][64];
  __shared__ float mli[64];

  int tid = threadIdx.x, lane = tid & 63, w = tid >> 6;
  int wr = w >> 1, wc = w & 1;

#define STAGE_K(kt_, buf_)                                                      \
  { _Pragma("unroll")                                                           \
    for (int t = 0; t < 2; ++t){                                                \
      int seg = w*2 + t;                                                        \
      int row = seg*2 + (lane >> 5);                                            \
      int cb  = ((lane & 31)*16) ^ ((row & 7) << 4);                            \
      gload16(Kh + (long)((kt_)*32 + row)*HDIM + (cb >> 1),                     \
              (char*)lK[buf_] + seg*1024);                                      \
    } }

#define QKT(buf_)                                                               \
  { _Pragma("unroll")                                                           \
    for (int kk = 0; kk < 8; ++kk){                                             \
      int rk = wc*16 + (lane & 15);                                             \
      bf16x8 bk = *(const bf16x8*)((const char*)lK[buf_] + rk*512 +             \
                   ((kk*64 + (lane >> 4)*16) ^ ((rk & 7) << 4)));               \
      accs = __builtin_amdgcn_mfma_f32_16x16x32_bf16(aq[kk], bk, accs, 0, 0, 0);\
    } }

  // ---- Q fragments into registers (once; reused in both sweeps) ----
  bf16x8 aq[8];
  {
    const unsigned short* qrow = Qh + (long)(qbase + wr*16 + (lane & 15))*HID + (lane >> 4)*8;
    #pragma unroll
    for (int kk = 0; kk < 8; ++kk)
      aq[kk] = *(const bf16x8*)(qrow + kk*32);
  }

  f32x4 accs;
  f32x4 acc_o[4][2];
  float oL[4];
  #pragma unroll
  for (int q = 0; q < 4; ++q){ accs[q] = 0.f; oL[q] = 0.f; }
  #pragma unroll
  for (int m = 0; m < 4; ++m)
    #pragma unroll
    for (int n = 0; n < 2; ++n)
      #pragma unroll
      for (int q = 0; q < 4; ++q) acc_o[m][n][q] = 0.f;

  // ---------------- sweep 1: l-sums + unnormalized PV ----------------
  STAGE_K(0, 0)
  STAGE_K(1, 1)
  asm volatile("s_waitcnt vmcnt(2)" ::: "memory");
  __builtin_amdgcn_s_barrier();
  for (int kt = 0; kt < T; ++kt){
    __builtin_amdgcn_s_setprio(1);
    QKT(kt & 1)
    __builtin_amdgcn_s_setprio(0);
    if (kt*32 + wc*16 + 15 <= qbase + wr*16){      // wave-uniform: fully valid
      #pragma unroll
      for (int ri = 0; ri < 4; ++ri){
        int rowl = wr*16 + (lane >> 4)*4 + ri;
        int coll = wc*16 + (lane & 15);
        float e = __expf(accs[ri]*0.0625f - 8.0f);
        oL[ri] += e;
        lA[kt & 1][rowl*40 + coll] = (__bf16)e;
        accs[ri] = 0.f;
      }
    } else {
      #pragma unroll
      for (int ri = 0; ri < 4; ++ri){
        int rowl = wr*16 + (lane >> 4)*4 + ri;
        int coll = wc*16 + (lane & 15);
        float e = (kt*32 + coll <= qbase + rowl) ? __expf(accs[ri]*0.0625f - 8.0f) : 0.f;
        oL[ri] += e;
        lA[kt & 1][rowl*40 + coll] = (__bf16)e;
        accs[ri] = 0.f;
      }
    }
    bf16x8 vf0 = *(const bf16x8*)(Vh + (long)(w*32 +      (lane & 15))*SEQ + kt*32 + (lane >> 4)*8);
    bf16x8 vf1 = *(const bf16x8*)(Vh + (long)(w*32 + 16 + (lane & 15))*SEQ + kt*32 + (lane >> 4)*8);
    asm volatile("s_waitcnt lgkmcnt(0)" ::: "memory");
    asm volatile("s_waitcnt vmcnt(2)" ::: "memory");
    __builtin_amdgcn_s_barrier();
    if (kt + 2 < T) STAGE_K(kt + 2, kt & 1)
    __builtin_amdgcn_s_setprio(1);
    #pragma unroll
    for (int m2 = 0; m2 < 4; ++m2){
      int rq = m2*16 + (lane & 15);
      bf16x8 ap = *(const bf16x8*)&lA[kt & 1][rq*40 + (lane >> 4)*8];
      acc_o[m2][0] = __builtin_amdgcn_mfma_f32_16x16x32_bf16(ap, vf0, acc_o[m2][0], 0, 0, 0);
      acc_o[m2][1] = __builtin_amdgcn_mfma_f32_16x16x32_bf16(ap, vf1, acc_o[m2][1], 0, 0, 0);
    }
    __builtin_amdgcn_s_setprio(0);
  }

  // ---------------- l reduce -> mli ----------------
  #pragma unroll
  for (int ri = 0; ri < 4; ++ri){
    float v = oL[ri];
    #pragma unroll
    for (int off = 1; off < 16; off <<= 1) v += __shfl_xor(v, off);
    if ((lane & 15) == 0)
      lWl[w][wr*16 + (lane >> 4)*4 + ri] = v;
  }
  __syncthreads();
  if (tid < 64){
    int g = (tid >> 4) * 2;
    mli[tid] = 1.0f / (lWl[g][tid] + lWl[g+1][tid]);
  }
  __syncthreads();

  float ils[4];
  #pragma unroll
  for (int ri = 0; ri < 4; ++ri)
    ils[ri] = mli[wr*16 + (lane >> 4)*4 + ri];

  // ---------------- O epilogue: AO = (E@V) * il ----------------
  #pragma unroll
  for (int m2 = 0; m2 < 4; ++m2){
    #pragma unroll
    for (int ri = 0; ri < 4; ++ri){
      int row = m2*16 + (lane >> 4)*4 + ri;
      float il = mli[row];
      long gr = (long)b*SEQ + qbase + row;
      #pragma unroll
      for (int n = 0; n < 2; ++n){
        int col = w*32 + n*16 + (lane & 15);
        AOb[gr*HID + h*HDIM + col] = f2bf(acc_o[m2][n][ri] * il);
      }
    }
  }

  // ---------------- sweep 2: recompute + write P directly ----------------
  STAGE_K(0, 0)
  STAGE_K(1, 1)
  asm volatile("s_waitcnt vmcnt(2)" ::: "memory");
  __builtin_amdgcn_s_barrier();
  for (int kt = 0; kt < T; ++kt){
    __builtin_amdgcn_s_setprio(1);
    QKT(kt & 1)
    __builtin_amdgcn_s_setprio(0);
    if (kt*32 + wc*16 + 15 <= qbase + wr*16){      // wave-uniform: fully valid
      #pragma unroll
      for (int ri = 0; ri < 4; ++ri){
        int rowl = wr*16 + (lane >> 4)*4 + ri;
        int coll = wc*16 + (lane & 15);
        Sh[(long)(qbase + rowl)*SEQ + kt*32 + coll] =
            __expf(accs[ri]*0.0625f - 8.0f) * ils[ri];
        accs[ri] = 0.f;
      }
    } else {
      #pragma unroll
      for (int ri = 0; ri < 4; ++ri){
        int rowl = wr*16 + (lane >> 4)*4 + ri;
        int coll = wc*16 + (lane & 15);
        float p = (kt*32 + coll <= qbase + rowl)
                  ? __expf(accs[ri]*0.0625f - 8.0f) * ils[ri] : 0.f;
        Sh[(long)(qbase + rowl)*SEQ + kt*32 + coll] = p;
        accs[ri] = 0.f;
      }
    }
    asm volatile("s_waitcnt vmcnt(4)" ::: "memory");
    __builtin_amdgcn_s_barrier();
    if (kt + 2 < T) STAGE_K(kt + 2, kt & 1)
  }

  // ---------------- zero tail ----------------
  {
    f32x4 z4; z4[0]=0.f; z4[1]=0.f; z4[2]=0.f; z4[3]=0.f;
    int row = qbase + (tid >> 3);
    for (int c = T*32 + (tid & 7)*4; c < SEQ; c += 32)
      *(f32x4*)&Sh[(long)row*SEQ + c] = z4;
  }
#undef STAGE_K
#undef QKT
}

// ---- 256x128 deep-pipelined GEMM (8 waves, BK=64, dbuf LDS, counted vmcnt) ----
// (R11/R16 version — proven best)
template<int OUTF32>
__global__ __launch_bounds__(512, 1)
void gemm256(const unsigned short* __restrict__ A16, const unsigned short* __restrict__ BT,
             void* __restrict__ Cv, int lda, int ldb, int ldc, int K){
  constexpr int BM = 256, BN = 128, BK = 64;
  int m0 = blockIdx.x * BM, n0 = blockIdx.y * BN;

  __shared__ unsigned short lA[2][BM*BK];
  __shared__ unsigned short lB[2][BN*BK];

  int tid = threadIdx.x, lane = tid & 63, w = tid >> 6;
  int wr = w >> 1, wc = w & 1;
  int srow = lane >> 3;
  int vswz = ((lane & 7) ^ ((lane >> 3) & 7)) * 8;

  f32x4 acc[4][4];
  #pragma unroll
  for (int m = 0; m < 4; ++m)
    #pragma unroll
    for (int n = 0; n < 4; ++n)
      #pragma unroll
      for (int q = 0; q < 4; ++q) acc[m][n][q] = 0.f;

  int NT = K / BK;

#define STAGE256(kt_, buf_)                                                    \
  { int k0_ = (kt_) * BK;                                                      \
    _Pragma("unroll")                                                          \
    for (int t = 0; t < 4; ++t){                                               \
      int seg = w*4 + t;                                                       \
      const unsigned short* src = A16 + (long)(m0 + seg*8 + srow)*lda + k0_ + vswz; \
      gload16(src, (char*)lA[buf_] + seg*1024);                                \
    }                                                                          \
    _Pragma("unroll")                                                          \
    for (int t = 0; t < 2; ++t){                                               \
      int seg = w*2 + t;                                                       \
      const unsigned short* src = BT + (long)(n0 + seg*8 + srow)*ldb + k0_ + vswz; \
      gload16(src, (char*)lB[buf_] + seg*1024);                                \
    } }

  STAGE256(0, 0)
  STAGE256(1, 1)
  int cur = 0;

  for (int kt = 0; kt < NT; ++kt){
    if (kt < NT - 1) asm volatile("s_waitcnt vmcnt(6)" ::: "memory");
    else             asm volatile("s_waitcnt vmcnt(0)" ::: "memory");
    __builtin_amdgcn_s_barrier();

    const char* La = (const char*)lA[cur];
    const char* Lb = (const char*)lB[cur];
    __builtin_amdgcn_s_setprio(1);
    #pragma unroll
    for (int kk = 0; kk < 2; ++kk){
      bf16x8 af[4], bfr[4];
      #pragma unroll
      for (int m = 0; m < 4; ++m){
        int row = wr*64 + m*16 + (lane & 15);
        int kb = (kk*64 + (lane >> 4)*16) ^ ((row & 7) << 4);
        af[m] = *(const bf16x8*)(La + row*128 + kb);
      }
      #pragma unroll
      for (int n = 0; n < 4; ++n){
        int row = wc*64 + n*16 + (lane & 15);
        int kb = (kk*64 + (lane >> 4)*16) ^ ((row & 7) << 4);
        bfr[n] = *(const bf16x8*)(Lb + row*128 + kb);
      }
      #pragma unroll
      for (int m = 0; m < 4; ++m)
        #pragma unroll
        for (int n = 0; n < 4; ++n)
          acc[m][n] = __builtin_amdgcn_mfma_f32_16x16x32_bf16(af[m], bfr[n], acc[m][n], 0, 0, 0);
    }
    __builtin_amdgcn_s_setprio(0);
    __builtin_amdgcn_s_barrier();
    if (kt + 2 < NT) STAGE256(kt + 2, cur)
    cur ^= 1;
  }
#undef STAGE256

  #pragma unroll
  for (int m = 0; m < 4; ++m){
    #pragma unroll
    for (int ri = 0; ri < 4; ++ri){
      int orow = m0 + wr*64 + m*16 + (lane >> 4)*4 + ri;
      #pragma unroll
      for (int n = 0; n < 4; ++n){
        int ocol = n0 + wc*64 + n*16 + (lane & 15);
        float vv = acc[m][n][ri];
        if (OUTF32) ((float*)Cv)[(long)orow*ldc + ocol] = vv;
        else        ((unsigned short*)Cv)[(long)orow*ldc + ocol] = f2bf(vv);
      }
    }
  }
}

extern "C" void kernel_launch(void* const* d_in, const int* in_sizes, int n_in,
                              void* d_out, int out_size, void* d_ws, size_t ws_size,
                              hipStream_t stream){
  const float* hs  = (const float*)d_in[0];
  const int*   pos = (const int*)  d_in[1];
  const float* Wq  = (const float*)d_in[3];
  const float* Wk  = (const float*)d_in[4];
  const float* Wv  = (const float*)d_in[5];
  const float* Wo  = (const float*)d_in[6];

  float* out  = (float*)d_out;
  float* Sbuf = out + (long)ROWS * HID;

  unsigned short* wsp   = (unsigned short*)d_ws;
  unsigned short* hsb   = wsp;
  unsigned short* wqkvT = hsb   + (long)ROWS*HID;
  unsigned short* woT   = wqkvT + (long)QKVN*HID;
  unsigned short* qkvb  = woT   + (long)HID*HID;
  unsigned short* Qb    = qkvb  + (long)ROWS*QKVN;
  unsigned short* Kb    = Qb    + (long)ROWS*HID;
  unsigned short* VT    = Kb    + (long)ROWS*HDIM;
  unsigned short* AOb   = VT    + (long)BATCH*HDIM*SEQ;

  // 1. hs convert + all weight transposes (one dispatch)
  k_prep<<<2048 + 9216, 256, 0, stream>>>(hs, hsb, Wq, Wk, Wv, Wo, wqkvT, woT);

  // 2. QKV projection
  gemm256<0><<<dim3(ROWS/256, QKVN/128), 512, 0, stream>>>(
      hsb, wqkvT, qkvb, HID, HID, QKVN, HID);

  // 3. RoPE (Q,K) + V transpose (one dispatch)
  k_mid<<<ROWS + 1024, 256, 0, stream>>>(qkvb, pos, Qb, Kb, VT);

  // 4. fused scores + softmax + PV (S written once, never re-read)
  k_fused<<<dim3(NBH, 32), 512, 0, stream>>>(Qb, Kb, VT, Sbuf, AOb);

  // 5. out = attn_out @ Wo
  gemm256<1><<<dim3(ROWS/256, HID/128), 512, 0, stream>>>(
      AOb, woT, out, HID, HID, HID, HID);
}